// Round 7
// baseline (451.961 us; speedup 1.0000x reference)
//
#include <hip/hip_runtime.h>
#include <hip/hip_bf16.h>
#include <cstdint>

#define DEVI __device__ __forceinline__

typedef __attribute__((ext_vector_type(8))) short bf16x8;
typedef __attribute__((ext_vector_type(4))) float f32x4;

DEVI float bf2f(unsigned short u) {
    union { unsigned int i; float f; } v; v.i = ((unsigned int)u) << 16; return v.f;
}
DEVI float ldf(const void* p, long long i, int f32) {
    return f32 ? ((const float*)p)[i] : bf2f(((const unsigned short*)p)[i]);
}
DEVI unsigned short f2bfu(float x) {
    __hip_bfloat16 h = __float2bfloat16(x);
    return *reinterpret_cast<unsigned short*>(&h);
}
DEVI short f2bf(float x) { return (short)f2bfu(x); }
DEVI float eluf(float x) { return x > 0.f ? x : __expf(x) - 1.f; }

// ---- flag detection: flags[0]=edge_index is int64, flags[1]=floats are fp32
__global__ __launch_bounds__(64) void detect_k(
    const int* __restrict__ eidx32, const unsigned int* __restrict__ wbits,
    int* __restrict__ flags)
{
    int t = threadIdx.x;
    int odd = eidx32[2 * t + 1];
    unsigned long long bz = __ballot(odd == 0);
    unsigned int w = wbits[t];
    unsigned int ex = (w >> 23) & 0xFF;
    unsigned long long bf = __ballot(ex >= 100 && ex <= 130);
    if (t == 0) {
        flags[0] = (bz == ~0ULL) ? 1 : 0;
        flags[1] = (__popcll(bf) >= 48) ? 1 : 0;
    }
}

// -------------- Kernel 1: node pathway -> qkv_bf16[M,64] --------------------
__global__ __launch_bounds__(256) void node_qkv_k(
    const int* __restrict__ flags,
    const void* __restrict__ evec,
    const void* __restrict__ W1, const void* __restrict__ b1,
    const void* __restrict__ W2, const void* __restrict__ b2,
    const void* __restrict__ W,  const void* __restrict__ b,
    unsigned short* __restrict__ qkvb, int M_)
{
    __shared__ float sW[1024], sW2[64], sb[64], sb2[16], sW1[4], sb1[4];
    int t = threadIdx.x;
    int f32 = flags[1];
    for (int i = t; i < 1024; i += 256) sW[i] = ldf(W, i, f32);
    if (t < 64) { sW2[t] = ldf(W2, t, f32); sb[t] = ldf(b, t, f32); }
    if (t < 16) sb2[t] = ldf(b2, t, f32);
    if (t < 4)  { sW1[t] = ldf(W1, t, f32); sb1[t] = ldf(b1, t, f32); }
    __syncthreads();

    int m = blockIdx.x * 256 + t;
    if (m >= M_) return;

    float x = ldf(evec, m, f32);
    float h1[4];
    #pragma unroll
    for (int j = 0; j < 4; ++j) h1[j] = eluf(fmaf(x, sW1[j], sb1[j]));
    float h2[16];
    #pragma unroll
    for (int k = 0; k < 16; ++k) h2[k] = sb2[k];
    #pragma unroll
    for (int j = 0; j < 4; ++j)
        #pragma unroll
        for (int k = 0; k < 16; ++k) h2[k] = fmaf(h1[j], sW2[j*16 + k], h2[k]);

    uint4* op = (uint4*)(qkvb + (size_t)m * 64);
    for (int g = 0; g < 8; ++g) {
        float v[8];
        #pragma unroll
        for (int j = 0; j < 8; ++j) {
            int c = g * 8 + j;
            float a = sb[c];
            #pragma unroll
            for (int k = 0; k < 16; ++k) a = fmaf(h2[k], sW[k*64 + c], a);
            v[j] = a;
        }
        uint4 pk;
        pk.x = (unsigned)f2bfu(v[0]) | ((unsigned)f2bfu(v[1]) << 16);
        pk.y = (unsigned)f2bfu(v[2]) | ((unsigned)f2bfu(v[3]) << 16);
        pk.z = (unsigned)f2bfu(v[4]) | ((unsigned)f2bfu(v[5]) << 16);
        pk.w = (unsigned)f2bfu(v[6]) | ((unsigned)f2bfu(v[7]) << 16);
        op[g] = pk;
    }
}

// ---------------- Kernel 2: histogram of dst ----------------
__global__ __launch_bounds__(256) void hist_k(
    const int* __restrict__ flags, const int* __restrict__ eidx32,
    int* __restrict__ counts, int NE_)
{
    int e = blockIdx.x * 256 + threadIdx.x;
    if (e >= NE_) return;
    int i64 = flags[0];
    int dst = i64 ? eidx32[2LL * (NE_ + (long long)e)] : eidx32[(long long)NE_ + e];
    atomicAdd(&counts[dst], 1);
}

// ---------------- Kernel 3a: per-1024-tile block sums ----------------
__global__ __launch_bounds__(256) void scan_a_k(
    const int* __restrict__ counts, int* __restrict__ bsum, int M_)
{
    __shared__ int s[256];
    int t = threadIdx.x;
    int g4 = blockIdx.x * 256 + t;
    int i0 = g4 * 4;
    int v = 0;
    if (i0 + 3 < M_) {
        int4 c = ((const int4*)counts)[g4];
        v = c.x + c.y + c.z + c.w;
    } else {
        for (int k = 0; k < 4 && i0 + k < M_; ++k) v += counts[i0 + k];
    }
    s[t] = v; __syncthreads();
    for (int off = 128; off > 0; off >>= 1) {
        if (t < off) s[t] += s[t + off];
        __syncthreads();
    }
    if (t == 0) bsum[blockIdx.x] = s[0];
}

// ---------------- Kernel 3b: scan block sums (nb <= 256) ----------------
__global__ __launch_bounds__(256) void scan_b_k(
    const int* __restrict__ bsum, int* __restrict__ bexcl, int nb,
    int* __restrict__ offsets, int M_, int NE_)
{
    __shared__ int s[256];
    int t = threadIdx.x;
    int mine = (t < nb) ? bsum[t] : 0;
    s[t] = mine; __syncthreads();
    for (int off = 1; off < 256; off <<= 1) {
        int v = (t >= off) ? s[t - off] : 0;
        __syncthreads();
        s[t] += v;
        __syncthreads();
    }
    if (t < nb) bexcl[t] = s[t] - mine;
    if (t == 0) offsets[M_] = NE_;
}

// ---------------- Kernel 3c: final offsets + cursor ----------------
__global__ __launch_bounds__(256) void scan_c_k(
    const int* __restrict__ counts, const int* __restrict__ bexcl,
    int* __restrict__ offsets, int* __restrict__ cursor, int M_)
{
    __shared__ int s[256];
    int t = threadIdx.x;
    int g4 = blockIdx.x * 256 + t;
    int i0 = g4 * 4;
    int c0 = 0, c1 = 0, c2 = 0, c3 = 0;
    if (i0 + 3 < M_) {
        int4 c = ((const int4*)counts)[g4];
        c0 = c.x; c1 = c.y; c2 = c.z; c3 = c.w;
    } else {
        if (i0 + 0 < M_) c0 = counts[i0 + 0];
        if (i0 + 1 < M_) c1 = counts[i0 + 1];
        if (i0 + 2 < M_) c2 = counts[i0 + 2];
        if (i0 + 3 < M_) c3 = counts[i0 + 3];
    }
    int tsum = c0 + c1 + c2 + c3;
    s[t] = tsum; __syncthreads();
    for (int off = 1; off < 256; off <<= 1) {
        int v = (t >= off) ? s[t - off] : 0;
        __syncthreads();
        s[t] += v;
        __syncthreads();
    }
    int run = bexcl[blockIdx.x] + s[t] - tsum;
    if (i0 + 0 < M_) { offsets[i0+0] = run; cursor[i0+0] = run; run += c0; }
    if (i0 + 1 < M_) { offsets[i0+1] = run; cursor[i0+1] = run; run += c1; }
    if (i0 + 2 < M_) { offsets[i0+2] = run; cursor[i0+2] = run; run += c2; }
    if (i0 + 3 < M_) { offsets[i0+3] = run; cursor[i0+3] = run; run += c3; }
}

// --- Kernel 4: scatter records {src, dst, efeat(4xbf16)} grouped by dst -----
__global__ __launch_bounds__(256) void scatter_k(
    const int* __restrict__ flags, const int* __restrict__ eidx32,
    const void* __restrict__ efeat,
    int* __restrict__ cursor, int4* __restrict__ sorted, int NE_)
{
    int e = blockIdx.x * 256 + threadIdx.x;
    if (e >= NE_) return;
    int i64 = flags[0];
    int f32 = flags[1];
    int src, dst;
    if (i64) { src = eidx32[2LL * e]; dst = eidx32[2LL * (NE_ + (long long)e)]; }
    else     { src = eidx32[e];       dst = eidx32[(long long)NE_ + e]; }

    unsigned int ef01, ef23;
    if (f32) {
        const float4 f = ((const float4*)efeat)[e];
        ef01 = (unsigned)f2bfu(f.x) | ((unsigned)f2bfu(f.y) << 16);
        ef23 = (unsigned)f2bfu(f.z) | ((unsigned)f2bfu(f.w) << 16);
    } else {
        const uint2 u = ((const uint2*)efeat)[e];
        ef01 = u.x; ef23 = u.y;
    }

    int pos = atomicAdd(&cursor[dst], 1);
    sorted[pos] = make_int4(src, dst, (int)ef01, (int)ef23);
}

// -- Kernel 5: FUSED scores (MFMA) + segment accumulate + output MLP ---------
// one wave handles 16 consecutive dsts; chunks of 16 sorted records
__global__ __launch_bounds__(256) void fused_k(
    const int* __restrict__ flags,
    const int* __restrict__ offsets, const int4* __restrict__ sorted,
    const void* __restrict__ W2, const void* __restrict__ b2,
    const void* __restrict__ W,  const void* __restrict__ b,
    const unsigned short* __restrict__ qkvb,
    const void* __restrict__ Wout, const void* __restrict__ bout,
    const void* __restrict__ Wout1, const void* __restrict__ bout1,
    void* __restrict__ out, int M_)
{
    __shared__ float sW2[64], sb2[16];
    __shared__ float sWo[1024], sbo[16], sWo1[16];
    __shared__ float sbo1;
    __shared__ float sE[4][16 * 68];      // per-wave E tile, stride 68
    __shared__ float sS[4][64];           // per-wave scores [j][h]
    __shared__ int   sSrc[4][16];         // per-wave src ids

    int t = threadIdx.x;
    int f32 = flags[1];
    for (int i = t; i < 1024; i += 256) sWo[i] = ldf(Wout, i, f32);
    if (t < 64) sW2[t] = ldf(W2, t, f32);
    if (t < 16) { sb2[t] = ldf(b2, t, f32); sbo[t] = ldf(bout, t, f32); sWo1[t] = ldf(Wout1, t, f32); }
    if (t == 0) sbo1 = ldf(bout1, 0, f32);
    __syncthreads();

    int wvi  = t >> 6;
    int lane = t & 63;
    int col  = lane & 15;
    int quad = lane >> 4;
    float* myE  = &sE[wvi][0];
    float* myS  = &sS[wvi][0];
    int*   mySrc = &sSrc[wvi][0];

    // loop-invariant B fragments + bias (phase 1)
    bf16x8 bfrag[4];
    float  bb[4];
    #pragma unroll
    for (int h = 0; h < 4; ++h) {
        #pragma unroll
        for (int jj = 0; jj < 8; ++jj) {
            int k = quad * 8 + jj;
            float wv_ = (k < 16) ? ldf(W, k * 64 + h * 16 + col, f32) : 0.f;
            bfrag[h][jj] = f2bf(wv_);
        }
        bb[h] = ldf(b, h * 16 + col, f32);
    }

    int m0 = (blockIdx.x * 4 + wvi) * 16;
    if (m0 >= M_) return;
    int mtop = m0 + 16; if (mtop > M_) mtop = M_;
    int beg = offsets[m0], end = offsets[mtop];

    int j2 = lane >> 2, h2 = lane & 3;        // phase-2/3 lane = (j|i, h)
    int m = m0 + j2;
    bool valid = (m < M_);
    int sbm = valid ? offsets[m]     : 0;
    int sem = valid ? offsets[m + 1] : 0;

    float acc[16];
    #pragma unroll
    for (int d = 0; d < 16; ++d) acc[d] = 0.f;
    float z = 0.f;

    for (int c = beg; c < end; c += 16) {
        // ---- phase 1: records + e16 + MFMA E
        int jA = c + col;
        int4 rec = make_int4(0, 0, 0, 0);
        if (jA < end) rec = sorted[jA];
        float ef0 = bf2f((unsigned short)((unsigned)rec.z & 0xffff));
        float ef1 = bf2f((unsigned short)((unsigned)rec.z >> 16));
        float ef2 = bf2f((unsigned short)((unsigned)rec.w & 0xffff));
        float ef3 = bf2f((unsigned short)((unsigned)rec.w >> 16));

        bf16x8 afrag;
        #pragma unroll
        for (int jj = 0; jj < 8; ++jj) {
            int k = quad * 8 + jj;
            float v = 0.f;
            if (k < 16) {
                v = eluf(fmaf(ef0, sW2[k],
                        fmaf(ef1, sW2[16 + k],
                        fmaf(ef2, sW2[32 + k],
                        fmaf(ef3, sW2[48 + k], sb2[k])))));
            }
            afrag[jj] = f2bf(v);
        }

        f32x4 a4[4];
        #pragma unroll
        for (int h = 0; h < 4; ++h) {
            a4[h] = (f32x4){0.f, 0.f, 0.f, 0.f};
            a4[h] = __builtin_amdgcn_mfma_f32_16x16x32_bf16(afrag, bfrag[h], a4[h], 0, 0, 0);
        }

        #pragma unroll
        for (int h = 0; h < 4; ++h)
            #pragma unroll
            for (int r = 0; r < 4; ++r)
                myE[(quad * 4 + r) * 68 + h * 16 + col] = a4[h][r] + bb[h];
        if (lane < 16) mySrc[col] = rec.x;
        asm volatile("s_waitcnt lgkmcnt(0)" ::: "memory");

        // ---- phase 2: lane (j2,h2): coalesced row loads + dot + exp
        int srcj = __shfl(rec.x, j2, 64);
        int dstj = __shfl(rec.y, j2, 64);
        const uint4* sp = (const uint4*)(qkvb + (size_t)srcj * 64 + h2 * 16);
        const uint4* dp = (const uint4*)(qkvb + (size_t)dstj * 64 + h2 * 16);
        uint4 sA = sp[0], sB = sp[1], dA = dp[0], dB = dp[1];

        const float4* ep = (const float4*)(myE + j2 * 68 + h2 * 16);
        float4 e0 = ep[0], e1 = ep[1], e2 = ep[2], e3 = ep[3];
        float E[16] = {e0.x,e0.y,e0.z,e0.w, e1.x,e1.y,e1.z,e1.w,
                       e2.x,e2.y,e2.z,e2.w, e3.x,e3.y,e3.z,e3.w};
        unsigned int su[8] = {sA.x,sA.y,sA.z,sA.w, sB.x,sB.y,sB.z,sB.w};
        unsigned int du[8] = {dA.x,dA.y,dA.z,dA.w, dB.x,dB.y,dB.z,dB.w};

        float sc = 0.f;
        #pragma unroll
        for (int i = 0; i < 8; ++i) {
            float s0 = bf2f((unsigned short)(su[i] & 0xffff));
            float s1 = bf2f((unsigned short)(su[i] >> 16));
            float d0 = bf2f((unsigned short)(du[i] & 0xffff));
            float d1 = bf2f((unsigned short)(du[i] >> 16));
            sc = fmaf(s0 * d0, E[2*i],   sc);
            sc = fmaf(s1 * d1, E[2*i+1], sc);
        }
        sc *= 0.25f;
        sc = fminf(fmaxf(sc, -5.f), 5.f);
        myS[j2 * 4 + h2] = __expf(sc);
        asm volatile("s_waitcnt lgkmcnt(0)" ::: "memory");

        // ---- phase 3: lane (j2=i, h2): my dst's sub-segment of this chunk
        int lo = sbm - c; if (lo < 0) lo = 0;
        int hi = sem - c; if (hi > 16) hi = 16;
        for (int jj = lo; jj < hi; ++jj) {
            float s = myS[jj * 4 + h2];
            int srcm = mySrc[jj];
            const uint4* p = (const uint4*)(qkvb + (size_t)srcm * 64 + h2 * 16);
            uint4 a0 = p[0], a1 = p[1];                 // L1/L2-hot (phase 2 read it)
            z += s;
            unsigned int q[8] = {a0.x,a0.y,a0.z,a0.w, a1.x,a1.y,a1.z,a1.w};
            #pragma unroll
            for (int i = 0; i < 8; ++i) {
                acc[2*i]   = fmaf(bf2f((unsigned short)(q[i] & 0xffff)), s, acc[2*i]);
                acc[2*i+1] = fmaf(bf2f((unsigned short)(q[i] >> 16)),    s, acc[2*i+1]);
            }
        }
    }

    if (!valid) return;

    // ---- epilogue: normalize + output MLP (reduce over the 4 head lanes)
    float zinv = 1.f / (z + 1e-6f);
    int hb = h2 * 16;
    float p[16];
    #pragma unroll
    for (int jj = 0; jj < 16; ++jj) p[jj] = 0.f;
    #pragma unroll
    for (int d = 0; d < 16; ++d) {
        float hv = acc[d] * zinv;
        #pragma unroll
        for (int jj = 0; jj < 16; ++jj) p[jj] = fmaf(hv, sWo[(hb + d) * 16 + jj], p[jj]);
    }
    #pragma unroll
    for (int jj = 0; jj < 16; ++jj) {
        p[jj] += __shfl_xor(p[jj], 1, 64);
        p[jj] += __shfl_xor(p[jj], 2, 64);
    }
    if (h2 == 0) {
        float o = sbo1;
        #pragma unroll
        for (int jj = 0; jj < 16; ++jj) o = fmaf(eluf(p[jj] + sbo[jj]), sWo1[jj], o);
        if (f32) ((float*)out)[m] = o;
        else     ((__hip_bfloat16*)out)[m] = __float2bfloat16(o);
    }
}

extern "C" void kernel_launch(void* const* d_in, const int* in_sizes, int n_in,
                              void* d_out, int out_size, void* d_ws, size_t ws_size,
                              hipStream_t stream)
{
    const int*  eidx  = (const int*)d_in[1];
    const void* efeat = d_in[2];
    const void* evec  = d_in[3];
    const void* W1 = d_in[4],  *b1 = d_in[5];
    const void* W2 = d_in[6],  *b2 = d_in[7];
    const void* W  = d_in[8],  *b  = d_in[9];
    const void* Wout = d_in[10], *bout = d_in[11];
    const void* Wout1 = d_in[12], *bout1 = d_in[13];

    const int M_  = in_sizes[3];       // 150000
    const int NE_ = in_sizes[1] / 2;   // 1500000
    const int nb  = (M_ + 1023) / 1024;

    // workspace layout (16B aligned); total ~45 MB
    char* wp = (char*)d_ws;
    int*            flags   = (int*)wp;                 wp += 16;
    unsigned short* qkvb    = (unsigned short*)wp;      wp += (size_t)M_ * 64 * 2;
    int*            counts  = (int*)wp;                 wp += (size_t)M_ * 4;
    int*            bsum    = (int*)wp;                 wp += 2048 * 4;
    int*            bexcl   = (int*)wp;                 wp += 2048 * 4;
    int*            offsets = (int*)wp;                 wp += ((size_t)M_ + 4) * 4;
    int*            cursor  = (int*)wp;                 wp += ((size_t)M_ + 4) * 4;
    int4*           sorted  = (int4*)wp;

    detect_k<<<1, 64, 0, stream>>>(eidx, (const unsigned int*)W, flags);
    hipMemsetAsync(counts, 0, (size_t)M_ * 4, stream);

    node_qkv_k<<<(M_ + 255) / 256, 256, 0, stream>>>(
        flags, evec, W1, b1, W2, b2, W, b, qkvb, M_);

    hist_k<<<(NE_ + 255) / 256, 256, 0, stream>>>(flags, eidx, counts, NE_);
    scan_a_k<<<nb, 256, 0, stream>>>(counts, bsum, M_);
    scan_b_k<<<1, 256, 0, stream>>>(bsum, bexcl, nb, offsets, M_, NE_);
    scan_c_k<<<nb, 256, 0, stream>>>(counts, bexcl, offsets, cursor, M_);
    scatter_k<<<(NE_ + 255) / 256, 256, 0, stream>>>(
        flags, eidx, efeat, cursor, sorted, NE_);

    int fblocks = (M_ + 63) / 64;     // 4 waves/block, 16 dsts/wave
    fused_k<<<fblocks, 256, 0, stream>>>(
        flags, offsets, sorted, W2, b2, W, b, qkvb,
        Wout, bout, Wout1, bout1, d_out, M_);
}